// Round 3
// baseline (26.291 us; speedup 1.0000x reference)
//
#include <hip/hip_runtime.h>

// Problem constants (fixed by setup_inputs)
constexpr int BSZ    = 32;                 // batch
constexpr int LCH    = 256;                // channels
constexpr int NPAIRS = (BSZ * (BSZ - 1)) / 2;   // 496 unordered pairs
constexpr int CK     = 32;                 // channels per chunk
constexpr int NCHUNK = LCH / CK;           // 8
constexpr int NBLK   = NPAIRS * NCHUNK;    // 3968

// total = 2 * sum_{i<j} sum_{k >= bins(i,j)} w[k] * sum_s |x[j,k,s]-x[i,k,s]|
//   w[k]      = 2^((255-k)/20)   (mean-normalization cancels in the ratio)
//   bins(i,j) = clip(ceil(log2(|ts_j-ts_i|+1)*20), 0, 256)
// out = total / 1024.  Average bins ~205 -> only ~20% of (pair,channel)
// cells are active; blocks skip inactive chunks entirely.

__global__ __launch_bounds__(256) void ts_cell_kernel(
    const float* __restrict__ latents,
    const int*   __restrict__ ts,
    float*       __restrict__ partial)
{
    const int blk  = blockIdx.x;
    const int p    = blk >> 3;        // pair 0..495
    const int c    = blk & 7;         // channel chunk 0..7
    const int tid  = threadIdx.x;     // 0..255
    const int site = tid & 127;       // float2 spatial site (256 floats/channel)
    const int slot = tid >> 7;        // channel parity slot (wave-uniform)

    // decode pair p -> (i, j), i<j   (p = 30i - i(i-1)/2 + j - 1)
    int i = 0;
    while (31 * (i + 1) - ((i + 1) * i) / 2 <= p) ++i;
    const int j = p - 30 * i + (i * (i - 1)) / 2 + 1;

    const float dt = fabsf((float)(ts[j] - ts[i])) + 1.0f;
    int bins = (int)ceilf(log2f(dt) * 20.0f);
    bins = min(max(bins, 0), LCH);

    const int kbase = c << 5;
    if (kbase + CK <= bins) {          // chunk fully gated off
        if (tid == 0) partial[blk] = 0.0f;
        return;
    }

    const float2* __restrict__ xi = (const float2*)latents + ((size_t)i << 15);
    const float2* __restrict__ xj = (const float2*)latents + ((size_t)j << 15);

    float acc = 0.0f;
#pragma unroll
    for (int it = 0; it < CK / 2; ++it) {
        const int k = kbase + (it << 1) + slot;
        if (k >= bins) {               // wave-uniform -> s_cbranch_execz skip
            const float wk = exp2f((float)(LCH - 1 - k) * 0.05f);
            const float2 a = xi[(k << 7) + site];
            const float2 b = xj[(k << 7) + site];
            acc = fmaf(wk, fabsf(a.x - b.x) + fabsf(a.y - b.y), acc);
        }
    }

    // block reduce: wave64 shuffle tree, then 4 wave sums via LDS
    for (int off = 32; off > 0; off >>= 1)
        acc += __shfl_down(acc, off, 64);
    __shared__ float wsum[4];
    if ((tid & 63) == 0) wsum[tid >> 6] = acc;
    __syncthreads();
    if (tid == 0) partial[blk] = wsum[0] + wsum[1] + wsum[2] + wsum[3];
}

__global__ __launch_bounds__(256) void ts_reduce_kernel(
    const float* __restrict__ partial,
    float*       __restrict__ out)
{
    const int t = threadIdx.x;   // 0..255
    double s = 0.0;
    for (int p = t; p < NBLK; p += 256) s += (double)partial[p];
    for (int off = 32; off > 0; off >>= 1)
        s += __shfl_down(s, off, 64);
    __shared__ double ds[4];
    if ((t & 63) == 0) ds[t >> 6] = s;
    __syncthreads();
    if (t == 0) out[0] = (float)((ds[0] + ds[1] + ds[2] + ds[3]) * (2.0 / 1024.0));
}

extern "C" void kernel_launch(void* const* d_in, const int* in_sizes, int n_in,
                              void* d_out, int out_size, void* d_ws, size_t ws_size,
                              hipStream_t stream)
{
    const float* latents = (const float*)d_in[0];
    const int*   ts      = (const int*)d_in[1];
    float*       out     = (float*)d_out;
    float*       partial = (float*)d_ws;   // NBLK floats of scratch

    ts_cell_kernel<<<NBLK, 256, 0, stream>>>(latents, ts, partial);
    ts_reduce_kernel<<<1, 256, 0, stream>>>(partial, out);
}

// Round 5
// 13.323 us; speedup vs baseline: 1.9734x; 1.9734x over previous
//
#include <hip/hip_runtime.h>

// Problem constants (fixed by setup_inputs)
constexpr int BSZ  = 32;                    // batch
constexpr int LCH  = 256;                   // channels
constexpr int NPAIRS = (BSZ * (BSZ - 1)) / 2;   // 496
constexpr int NQ   = 4;                     // pair quarters
constexpr int PQ   = NPAIRS / NQ;           // 124 pairs per block
constexpr int NBLK = LCH * NQ;              // 1024 blocks

// total = 2 * sum_{i<j} sum_{k >= bins(i,j)} w[k] * sum_s |x[j,k,s]-x[i,k,s]|
//   w[k]      = 2^((255-k)/20)   (mean-normalization cancels in the ratio)
//   bins(i,j) = clip(ceil(log2(|ts_j-ts_i|+1)*20), 0, 256)
// out = total / 1024
// Block = (channel k, pair-quarter q). Thread = one spatial site, all 32
// batch values in VGPRs (each input float read once from HBM, reused from
// registers). Gates = 124 bits in 4 uniform SGPRs via ballot; hot loop is
// sub+abs+select+fmac only — no LDS. All-zero-mask blocks skip everything.

__device__ __forceinline__ constexpr int pair_idx(int i, int j) {
    return 30 * i - (i * (i - 1)) / 2 + j - 1;   // i<j, p in [0,496)
}

template <int BASE>
__device__ __forceinline__ void accum_q(const float* __restrict__ x,
                                        const unsigned* __restrict__ m,
                                        float* __restrict__ acc) {
#pragma unroll
    for (int i = 0; i < BSZ - 1; ++i) {
#pragma unroll
        for (int j = i + 1; j < BSZ; ++j) {
            const int p = pair_idx(i, j);          // compile-time after unroll
            if (p >= BASE && p < BASE + PQ) {
                const int b = p - BASE;
                const float g = ((m[b >> 5] >> (b & 31)) & 1u) ? 1.0f : 0.0f;
                acc[b & 3] = fmaf(g, fabsf(x[i] - x[j]), acc[b & 3]);
            }
        }
    }
}

__global__ __launch_bounds__(256) void ts_main_kernel(
    const float* __restrict__ latents,
    const int*   __restrict__ ts,
    float*       __restrict__ partial)
{
    const int blk = blockIdx.x;
    const int k   = blk >> 2;        // channel 0..255
    const int q   = blk & 3;         // pair quarter 0..3
    const int tid = threadIdx.x;     // spatial site 0..255

    __shared__ unsigned lm[4];

    // ---- gates: bit b = (bins(pair q*PQ+b) <= k), b in [0,124) ----
    bool act = false;
    if (tid < PQ) {
        const int p = q * PQ + tid;
        int i = 0, s = 0;
        while (s + (31 - i) <= p) { s += 31 - i; ++i; }
        const int j = i + 1 + (p - s);
        const float dt = fabsf((float)(ts[j] - ts[i])) + 1.0f;
        int bins = (int)ceilf(log2f(dt) * 20.0f);
        bins = min(max(bins, 0), LCH);
        act = (bins <= k);
    }
    const unsigned long long bal = __ballot(act);
    if (tid == 0)       { lm[0] = (unsigned)bal; lm[1] = (unsigned)(bal >> 32); }
    else if (tid == 64) { lm[2] = (unsigned)bal; lm[3] = (unsigned)(bal >> 32); }
    __syncthreads();

    unsigned m[4];
#pragma unroll
    for (int c = 0; c < 4; ++c)
        m[c] = __builtin_amdgcn_readfirstlane(lm[c]);

    float res = 0.0f;
    if ((m[0] | m[1] | m[2] | m[3]) != 0u) {
        // all 32 batch values for (k, site=tid): coalesced, read once
        float x[BSZ];
#pragma unroll
        for (int b = 0; b < BSZ; ++b)
            x[b] = latents[((size_t)b << 16) + ((size_t)k << 8) + (size_t)tid];

        float acc[4] = {0.0f, 0.0f, 0.0f, 0.0f};
        switch (q) {
            case 0: accum_q<0>(x, m, acc);      break;
            case 1: accum_q<PQ>(x, m, acc);     break;
            case 2: accum_q<2 * PQ>(x, m, acc); break;
            default: accum_q<3 * PQ>(x, m, acc); break;
        }
        res = (acc[0] + acc[1]) + (acc[2] + acc[3]);
    }

    // ---- block reduce; apply channel weight once ----
    for (int off = 32; off > 0; off >>= 1)
        res += __shfl_down(res, off, 64);
    __shared__ float wsum[4];
    if ((tid & 63) == 0) wsum[tid >> 6] = res;
    __syncthreads();
    if (tid == 0) {
        const float wk = exp2f((float)(LCH - 1 - k) * 0.05f);
        partial[blk] = (wsum[0] + wsum[1] + wsum[2] + wsum[3]) * wk;
    }
}

__global__ __launch_bounds__(256) void ts_reduce_kernel(
    const float* __restrict__ partial,
    float*       __restrict__ out)
{
    const int t = threadIdx.x;   // 0..255
    double s = 0.0;
#pragma unroll
    for (int r = 0; r < NBLK / 256; ++r)
        s += (double)partial[t + 256 * r];
    for (int off = 32; off > 0; off >>= 1)
        s += __shfl_down(s, off, 64);
    __shared__ double ds[4];
    if ((t & 63) == 0) ds[t >> 6] = s;
    __syncthreads();
    if (t == 0)
        out[0] = (float)((((ds[0] + ds[1]) + (ds[2] + ds[3]))) * (2.0 / 1024.0));
}

extern "C" void kernel_launch(void* const* d_in, const int* in_sizes, int n_in,
                              void* d_out, int out_size, void* d_ws, size_t ws_size,
                              hipStream_t stream)
{
    const float* latents = (const float*)d_in[0];
    const int*   ts      = (const int*)d_in[1];
    float*       out     = (float*)d_out;
    float*       partial = (float*)d_ws;   // NBLK floats of scratch

    ts_main_kernel<<<NBLK, 256, 0, stream>>>(latents, ts, partial);
    ts_reduce_kernel<<<1, 256, 0, stream>>>(partial, out);
}